// Round 10
// baseline (123.381 us; speedup 1.0000x reference)
//
#include <hip/hip_runtime.h>
#include <math.h>

// Problem constants (match reference)
#define NB 16       // batch
#define NL 512      // rows per batch
#define NS 512      // samples per row
#define NE 3000     // ecdf grid points (3*N_REF)
#define NR 1000     // ref points
#define NROWS (NB * NL)
#define NBIN 512    // counting-sort bins (avg 1 sample/bin)
#define CPT 5       // fill cells per thread (stride-5 floats = conflict-free)

__device__ __forceinline__ float fast_rcp(float x) { return __builtin_amdgcn_rcpf(x); }

__global__ __launch_bounds__(256) void lcot_row_kernel(
    const float* __restrict__ x1, const float* __restrict__ x2,
    const float* __restrict__ ref, float* __restrict__ row_out)
{
    __shared__ float    s_sorted[NS];
    __shared__ unsigned s_hist[NBIN];       // histogram, then scatter cursor
    __shared__ unsigned s_prefix[NBIN + 1]; // exclusive prefix (stable)
    __shared__ float    s_ecdf[NE];         // filled only on [kmin,kmax)
    __shared__ float4   s_e14[NR / 4];      // e1 embedding (LDS, float4 access)
    __shared__ float    s_alpA[4], s_alpB[4];
    __shared__ float    s_devf[4];
    __shared__ unsigned s_wredu[4];
    float* s_e1 = (float*)s_e14;

    const int tid  = threadIdx.x;
    const int lane = tid & 63;
    const int wave = tid >> 6;
    const int row  = blockIdx.x;
    const float inv_n   = 1.0f / 512.0f;            // exact
    const float step    = (float)(3.0 / 2999.0);    // linspace(-1,2,3000) spacing
    const float invstep = 2999.0f / 3.0f;

    // preload this thread's 4 query refs once (threads 250..255 idle in inverse)
    const int j0 = tid * 4;
    float rj0 = 0.f, rj1 = 0.f, rj2 = 0.f, rj3 = 0.f;
    if (j0 < NR) {
        float4 r4 = ((const float4*)ref)[tid];
        rj0 = r4.x; rj1 = r4.y; rj2 = r4.z; rj3 = r4.w;
    }

    // prefetch BOTH rows up front (overlap HBM latency once)
    const float* srcA = x1 + (size_t)row * NS;
    const float* srcB = x2 + (size_t)row * NS;
    float a0 = srcA[tid], a1 = srcA[tid + 256];
    float c0 = srcB[tid], c1 = srcB[tid + 256];

    float acc = 0.0f;

    for (int inp = 0; inp < 2; ++inp) {
        float v0 = (inp == 0) ? a0 : c0;
        float v1 = (inp == 0) ? a1 : c1;

        if (inp == 0) {
            // zero histogram + BOTH inputs' alpha partial sums (once)
            s_hist[tid] = 0u;
            s_hist[tid + 256] = 0u;
            float sA = a0 + a1, sB = c0 + c1;
            #pragma unroll
            for (int o = 32; o > 0; o >>= 1) {
                sA += __shfl_down(sA, o, 64);
                sB += __shfl_down(sB, o, 64);
            }
            if (lane == 0) { s_alpA[wave] = sA; s_alpB[wave] = sB; }
            __syncthreads();                               // (A)
        }
        // (for inp==1: hist pre-zeroed during inp0's fill region, >=2 barriers ago)

        // ---- histogram ----
        int b0 = min((int)(v0 * 512.0f), NBIN - 1);
        int b1 = min((int)(v1 * 512.0f), NBIN - 1);
        atomicAdd(&s_hist[b0], 1u);
        atomicAdd(&s_hist[b1], 1u);
        __syncthreads();                                   // (B)

        const float* alp = (inp == 0) ? s_alpA : s_alpB;
        float alpha = (alp[0] + alp[1] + alp[2] + alp[3]) * inv_n - 0.5f;

        // ---- exclusive prefix over 512 bins ----
        unsigned h0 = s_hist[2 * tid];
        unsigned h1 = s_hist[2 * tid + 1];
        unsigned ls = h0 + h1;
        unsigned sc0 = ls;
        #pragma unroll
        for (int o = 1; o < 64; o <<= 1) {
            unsigned t2 = __shfl_up(sc0, o, 64);
            if (lane >= o) sc0 += t2;
        }
        if (lane == 63) s_wredu[wave] = sc0;
        __syncthreads();                                   // (C)
        unsigned wbase0 = 0;
        for (int w = 0; w < 4; ++w) if (w < wave) wbase0 += s_wredu[w];
        unsigned base = wbase0 + sc0 - ls;
        s_prefix[2 * tid]     = base;
        s_prefix[2 * tid + 1] = base + h0;
        s_hist[2 * tid]       = base;
        s_hist[2 * tid + 1]   = base + h0;
        if (tid == 255) s_prefix[NBIN] = (unsigned)NS;
        __syncthreads();                                   // (D)

        // ---- scatter + provisional node-deviation ----
        unsigned p0 = atomicAdd(&s_hist[b0], 1u);
        s_sorted[p0] = v0;
        unsigned p1 = atomicAdd(&s_hist[b1], 1u);
        s_sorted[p1] = v1;
        float dv = fmaxf(fabsf((float)(p0 + 1) * inv_n - v0),
                         fabsf((float)(p1 + 1) * inv_n - v1));
        #pragma unroll
        for (int o = 32; o > 0; o >>= 1) dv = fmaxf(dv, __shfl_down(dv, o, 64));
        if (lane == 0) s_devf[wave] = dv;
        __syncthreads();                                   // (E)

        // ---- per-bin insertion sort ----
        for (int bb = tid; bb < NBIN; bb += 256) {
            int beg = (int)s_prefix[bb];
            int end = (int)s_prefix[bb + 1];
            for (int i2 = beg + 1; i2 < end; ++i2) {
                float key = s_sorted[i2];
                int jj = i2 - 1;
                while (jj >= beg && s_sorted[jj] > key) { s_sorted[jj + 1] = s_sorted[jj]; --jj; }
                s_sorted[jj + 1] = key;
            }
        }
        __syncthreads();                                   // (F)

        // ---- deviation bound D ----
        float Dm = fmaxf(fmaxf(s_devf[0], s_devf[1]), fmaxf(s_devf[2], s_devf[3]));
        {
            float sa0 = s_sorted[0], sa1 = s_sorted[1];
            float sbA = s_sorted[510], sbB = s_sorted[511];
            float sl0 = inv_n * fast_rcp(sa1 - sa0);
            float slR = inv_n * fast_rcp(sbB - sbA);
            float lext = fabsf(inv_n - sl0 * sa0);
            float rext = fabsf(511.0f * inv_n + slR * (1.0f - sbA) - 1.0f);
            Dm = fmaxf(Dm, fmaxf(lext, rext));
        }
        float D = Dm + 0.0249f;   // provisional-rank slop + fp margin

        float qlo = 0.0f - alpha;
        float qhi = 0.999f - alpha;
        int kmin = max(0,  (int)((qlo + 1.0f - D) * invstep) - 2);
        int kmax = min(NE, (int)((qhi + 1.0f + D) * invstep) + 3);

        // ---- ECDF fill: fixed CPT cells/thread (stride-5 floats: conflict-free) ----
        {
            int k0 = kmin + tid * CPT;
            int k1 = min(k0 + CPT, kmax);
            float fm = -100.0f;
            int pos = 0;
            int ci = -1;
            float cx0 = 0.f, cy0 = 0.f, cslope = 0.f;
            for (int k = k0; k < k1; ++k) {
                float xn  = -1.0f + (float)k * step;
                float fm2 = floorf(xn);
                float r   = xn - fm2;
                if (fm2 != fm) {
                    fm = fm2;
                    int bq  = min((int)(r * 512.0f), NBIN - 1);
                    pos     = (int)s_prefix[bq];
                    int be  = (int)s_prefix[bq + 1];
                    while (pos < be && s_sorted[pos] < r) ++pos;
                } else {
                    while (pos < NS && s_sorted[pos] < r) ++pos;
                }
                int i = min(max(pos - 1, 0), NS - 2);
                if (i != ci) {
                    ci = i;
                    cx0 = s_sorted[i];
                    cy0 = (float)(i + 1) * inv_n;
                    cslope = inv_n * fast_rcp(s_sorted[i + 1] - cx0);
                }
                s_ecdf[k] = fm + (cy0 + cslope * (r - cx0));
            }
            // remainder coverage for pathological rows (W > 256*CPT): per-cell re-seed
            for (int k = kmin + 256 * CPT + tid; k < kmax; k += 256) {
                float xn  = -1.0f + (float)k * step;
                float fm2 = floorf(xn);
                float r   = xn - fm2;
                int bq  = min((int)(r * 512.0f), NBIN - 1);
                int pp  = (int)s_prefix[bq];
                int be  = (int)s_prefix[bq + 1];
                while (pp < be && s_sorted[pp] < r) ++pp;
                int i = min(max(pp - 1, 0), NS - 2);
                float x0 = s_sorted[i];
                float y0 = (float)(i + 1) * inv_n;
                float sl = inv_n * fast_rcp(s_sorted[i + 1] - x0);
                s_ecdf[k] = fm2 + (y0 + sl * (r - x0));
            }
        }
        // pre-zero histogram for input 2 (next use >= 2 barriers away)
        if (inp == 0) { s_hist[tid] = 0u; s_hist[tid + 256] = 0u; }
        __syncthreads();                                   // (G)

        // ---- bridge values, seed-routing thresholds, amb integer ranges ----
        const float INF = 3.0e38f;
        bool in0 = (kmin <= 999)  && (1000 < kmax);
        bool in1 = (kmin <= 1999) && (2000 < kmax);
        float t0a = in0 ? s_ecdf[999]  : 0.f;
        float t0b = in0 ? s_ecdf[1000] : 0.f;
        float t1a = in1 ? s_ecdf[1999] : 0.f;
        float t1b = in1 ? s_ecdf[2000] : 0.f;
        float rt0 = in0 ? t0b : ((kmin > 999)  ? -INF : INF);   // seed segment routing
        float rt1 = in1 ? t1b : ((kmin > 1999) ? -INF : INF);
        int jA0 = 1, jA1 = 0, jB0 = 1, jB1 = 0;                 // empty by default
        if (in0 && t0b < t0a) {
            jA0 = max((int)floorf((t0b + alpha) * 1000.0f) + 1, 0);
            jA1 = min((int)floorf((t0a + alpha) * 1000.0f), NR - 1);
        }
        if (in1 && t1b < t1a) {
            jB0 = max((int)floorf((t1b + alpha) * 1000.0f) + 1, 0);
            jB1 = min((int)floorf((t1a + alpha) * 1000.0f), NR - 1);
        }

        // ---- owner path: seed + local scan (non-amb queries only) ----
        if (j0 < NR) {
            float4 e1v4 = make_float4(0.f, 0.f, 0.f, 0.f);
            if (inp == 1) e1v4 = ((const float4*)s_e1)[tid];
            float o0 = 0.f, o1 = 0.f, o2 = 0.f, o3 = 0.f;   // inp0 results
            bool am0 = false, am1 = false, am2 = false, am3 = false;
            int  k = kmin;
            bool have = false;
            #pragma unroll
            for (int jj = 0; jj < 4; ++jj) {
                int  j  = j0 + jj;
                float rj = (jj == 0) ? rj0 : (jj == 1) ? rj1 : (jj == 2) ? rj2 : rj3;
                bool amb = (j >= jA0 && j <= jA1) || (j >= jB0 && j <= jB1);
                if (jj == 0) am0 = amb; else if (jj == 1) am1 = amb;
                else if (jj == 2) am2 = amb; else am3 = amb;
                if (!amb) {
                    float q = rj - alpha;
                    if (!have) {
                        int m = (q > rt0) + (q > rt1) - 1;
                        float u = q - (float)m;
                        int istar = min(max((int)ceilf(u * 512.0f) - 2, 0), NS - 2);
                        float xa = s_sorted[istar];
                        float xb = s_sorted[istar + 1];
                        float rstar = fmaf(u - (float)(istar + 1) * inv_n,
                                           512.0f * (xb - xa), xa);
                        float xstar = (float)m + rstar;
                        k = min(max((int)ceilf((xstar + 1.0f) * invstep) - 1, kmin), kmax - 2);
                        have = true;
                    }
                    while (k < kmax - 2 && s_ecdf[k + 1] < q) ++k;
                    while (k > kmin && s_ecdf[k] >= q) --k;
                    float e0  = s_ecdf[k];
                    float e1c = s_ecdf[k + 1];
                    float slope = step * fast_rcp(e1c - e0);
                    float xn0 = -1.0f + (float)k * step;
                    float embv = xn0 + slope * (q - e0) - rj;
                    if (inp == 0) {
                        if (jj == 0) o0 = embv; else if (jj == 1) o1 = embv;
                        else if (jj == 2) o2 = embv; else o3 = embv;
                    } else {
                        float ev = (jj == 0) ? e1v4.x : (jj == 1) ? e1v4.y
                                 : (jj == 2) ? e1v4.z : e1v4.w;
                        float d = fabsf(embv - ev);
                        float c = fminf(d, 1.0f - d);
                        acc = fmaf(c, c, acc);
                    }
                }
            }
            if (inp == 0) {
                if (!(am0 | am1 | am2 | am3)) {
                    ((float4*)s_e1)[tid] = make_float4(o0, o1, o2, o3);
                } else {
                    if (!am0) s_e1[j0]     = o0;
                    if (!am1) s_e1[j0 + 1] = o1;
                    if (!am2) s_e1[j0 + 2] = o2;
                    if (!am3) s_e1[j0 + 3] = o3;
                }
            }
        }

        // ---- amb handler: exact windowed array-bisect (r3 semantics), rare ----
        for (int pass = 0; pass < 2; ++pass) {
            int lo0 = pass ? jB0 : jA0;
            int hi0 = pass ? jB1 : jA1;
            for (int j = lo0 + tid; j <= hi0; j += 256) {
                float rj = ref[j];
                float q  = rj - alpha;
                int lo = kmin, hi = kmax;
                while (lo < hi) {
                    int mid = (lo + hi) >> 1;
                    if (s_ecdf[mid] < q) lo = mid + 1; else hi = mid;
                }
                int i = min(max(lo - 1, 0), NE - 2);
                float e0 = s_ecdf[i];
                float slope = step * fast_rcp(s_ecdf[i + 1] - e0);
                float xn0 = -1.0f + (float)i * step;
                float embv = xn0 + slope * (q - e0) - rj;
                if (inp == 0) {
                    s_e1[j] = embv;
                } else {
                    float d = fabsf(embv - s_e1[j]);
                    float c = fminf(d, 1.0f - d);
                    acc = fmaf(c, c, acc);
                }
            }
        }
        // NO end-of-input barrier needed (same argument as round 9): inp1's first
        // write to any array read here is separated by inp1's barriers B..G.
    }

    // ---- block reduce acc, sqrt, write per-row ----
    #pragma unroll
    for (int o = 32; o > 0; o >>= 1) acc += __shfl_down(acc, o, 64);
    if (lane == 0) s_devf[wave] = acc;
    __syncthreads();
    if (tid == 0) row_out[row] = sqrtf(s_devf[0] + s_devf[1] + s_devf[2] + s_devf[3]);
}

__global__ __launch_bounds__(256) void lcot_reduce_kernel(
    const float* __restrict__ row_vals, float* __restrict__ out)
{
    __shared__ float s_red[256];
    const int b = blockIdx.x;
    const int tid = threadIdx.x;
    float v = row_vals[b * NL + tid] + row_vals[b * NL + tid + 256];
    s_red[tid] = v;
    __syncthreads();
    for (int off = 128; off > 0; off >>= 1) {
        if (tid < off) s_red[tid] += s_red[tid + off];
        __syncthreads();
    }
    if (tid == 0) out[b] = s_red[0] * (1.0f / (float)NL);
}

extern "C" void kernel_launch(void* const* d_in, const int* in_sizes, int n_in,
                              void* d_out, int out_size, void* d_ws, size_t ws_size,
                              hipStream_t stream) {
    const float* x1  = (const float*)d_in[0];
    const float* x2  = (const float*)d_in[1];
    const float* ref = (const float*)d_in[2];
    float* out = (float*)d_out;
    float* row_vals = (float*)d_ws;   // NROWS floats of scratch

    lcot_row_kernel<<<NROWS, 256, 0, stream>>>(x1, x2, ref, row_vals);
    lcot_reduce_kernel<<<NB, 256, 0, stream>>>(row_vals, out);
}

// Round 11
// 118.701 us; speedup vs baseline: 1.0394x; 1.0394x over previous
//
#include <hip/hip_runtime.h>
#include <math.h>

// Problem constants (match reference)
#define NB 16       // batch
#define NL 512      // rows per batch
#define NS 512      // samples per row
#define NE 3000     // ecdf grid points (3*N_REF)
#define NR 1000     // ref points
#define NROWS (NB * NL)
#define NBIN 512    // counting-sort bins (avg 1 sample/bin)

__device__ __forceinline__ float fast_rcp(float x) { return __builtin_amdgcn_rcpf(x); }

__global__ __launch_bounds__(256) void lcot_row_kernel(
    const float* __restrict__ x1, const float* __restrict__ x2,
    const float* __restrict__ ref, float* __restrict__ row_out)
{
    __shared__ float    s_sorted[NS];
    __shared__ unsigned s_hist[NBIN];       // histogram, then scatter cursor
    __shared__ unsigned s_prefix[NBIN + 1]; // exclusive prefix (stable)
    __shared__ float    s_ecdf[NE];         // filled only on [kmin,kmax)
    __shared__ float    s_alpA[4], s_alpB[4]; // alpha partials per input
    __shared__ float    s_devf[4];          // dev partials / final acc partials
    __shared__ unsigned s_wredu[4];

    const int tid  = threadIdx.x;
    const int lane = tid & 63;
    const int wave = tid >> 6;
    const int row  = blockIdx.x;
    const float inv_n   = 1.0f / 512.0f;            // exact
    const float step    = (float)(3.0 / 2999.0);    // linspace(-1,2,3000) spacing
    const float invstep = 2999.0f / 3.0f;

    // preload this thread's 4 query refs once (threads 250..255 idle in inverse)
    const int j0 = tid * 4;
    float rj0 = 0.f, rj1 = 0.f, rj2 = 0.f, rj3 = 0.f;
    if (j0 < NR) {
        float4 r4 = ((const float4*)ref)[tid];
        rj0 = r4.x; rj1 = r4.y; rj2 = r4.z; rj3 = r4.w;
    }
    float e1r0 = 0.f, e1r1 = 0.f, e1r2 = 0.f, e1r3 = 0.f;   // e1 kept in registers

    // prefetch BOTH rows up front (overlap HBM latency once)
    const float* srcA = x1 + (size_t)row * NS;
    const float* srcB = x2 + (size_t)row * NS;
    float a0 = srcA[tid], a1 = srcA[tid + 256];
    float c0 = srcB[tid], c1 = srcB[tid + 256];

    float acc = 0.0f;

    for (int inp = 0; inp < 2; ++inp) {
        float v0 = (inp == 0) ? a0 : c0;
        float v1 = (inp == 0) ? a1 : c1;

        if (inp == 0) {
            // zero histogram + BOTH inputs' alpha partial sums (once)
            s_hist[tid] = 0u;
            s_hist[tid + 256] = 0u;
            float sA = a0 + a1, sB = c0 + c1;
            #pragma unroll
            for (int o = 32; o > 0; o >>= 1) {
                sA += __shfl_down(sA, o, 64);
                sB += __shfl_down(sB, o, 64);
            }
            if (lane == 0) { s_alpA[wave] = sA; s_alpB[wave] = sB; }
            __syncthreads();                               // (A)
        }
        // (for inp==1: hist pre-zeroed during inp0's fill region, >=2 barriers ago)

        // ---- histogram ----
        int b0 = min((int)(v0 * 512.0f), NBIN - 1);
        int b1 = min((int)(v1 * 512.0f), NBIN - 1);
        atomicAdd(&s_hist[b0], 1u);
        atomicAdd(&s_hist[b1], 1u);
        __syncthreads();                                   // (B)

        const float* alp = (inp == 0) ? s_alpA : s_alpB;
        float alpha = (alp[0] + alp[1] + alp[2] + alp[3]) * inv_n - 0.5f;

        // ---- exclusive prefix over 512 bins (2 consecutive bins / thread) ----
        unsigned h0 = s_hist[2 * tid];
        unsigned h1 = s_hist[2 * tid + 1];
        unsigned ls = h0 + h1;
        unsigned sc0 = ls;                                 // wave inclusive scan
        #pragma unroll
        for (int o = 1; o < 64; o <<= 1) {
            unsigned t2 = __shfl_up(sc0, o, 64);
            if (lane >= o) sc0 += t2;
        }
        if (lane == 63) s_wredu[wave] = sc0;
        __syncthreads();                                   // (C)
        unsigned wbase0 = 0;
        for (int w = 0; w < 4; ++w) if (w < wave) wbase0 += s_wredu[w];
        unsigned base = wbase0 + sc0 - ls;                 // exclusive base for bin 2*tid
        s_prefix[2 * tid]     = base;
        s_prefix[2 * tid + 1] = base + h0;
        s_hist[2 * tid]       = base;                      // scatter cursors
        s_hist[2 * tid + 1]   = base + h0;
        if (tid == 255) s_prefix[NBIN] = (unsigned)NS;
        __syncthreads();                                   // (D)

        // ---- scatter + PROVISIONAL node-deviation (slot vs true rank differ by
        //      <= bin_count-1; covered by +12/512 slop on D below) ----
        unsigned p0 = atomicAdd(&s_hist[b0], 1u);
        s_sorted[p0] = v0;
        unsigned p1 = atomicAdd(&s_hist[b1], 1u);
        s_sorted[p1] = v1;
        float dv = fmaxf(fabsf((float)(p0 + 1) * inv_n - v0),
                         fabsf((float)(p1 + 1) * inv_n - v1));
        #pragma unroll
        for (int o = 32; o > 0; o >>= 1) dv = fmaxf(dv, __shfl_down(dv, o, 64));
        if (lane == 0) s_devf[wave] = dv;
        __syncthreads();                                   // (E)

        // ---- per-bin insertion sort (exact; bins avg 1 element) ----
        for (int bb = tid; bb < NBIN; bb += 256) {
            int beg = (int)s_prefix[bb];
            int end = (int)s_prefix[bb + 1];
            for (int i2 = beg + 1; i2 < end; ++i2) {
                float key = s_sorted[i2];
                int jj = i2 - 1;
                while (jj >= beg && s_sorted[jj] > key) { s_sorted[jj + 1] = s_sorted[jj]; --jj; }
                s_sorted[jj + 1] = key;
            }
        }
        __syncthreads();                                   // (F)

        // ---- deviation bound D (node partials + exact extrapolation endpoints) ----
        float Dm = fmaxf(fmaxf(s_devf[0], s_devf[1]), fmaxf(s_devf[2], s_devf[3]));
        {
            float sa0 = s_sorted[0], sa1 = s_sorted[1];
            float sbA = s_sorted[510], sbB = s_sorted[511];
            float sl0 = inv_n * fast_rcp(sa1 - sa0);
            float slR = inv_n * fast_rcp(sbB - sbA);
            float lext = fabsf(inv_n - sl0 * sa0);
            float rext = fabsf(511.0f * inv_n + slR * (1.0f - sbA) - 1.0f);
            Dm = fmaxf(Dm, fmaxf(lext, rext));
        }
        float D = Dm + 0.0249f;   // provisional-rank slop + fp margin

        float qlo = 0.0f - alpha;
        float qhi = 0.999f - alpha;
        int kmin = max(0,  (int)((qlo + 1.0f - D) * invstep) - 2);
        int kmax = min(NE, (int)((qhi + 1.0f + D) * invstep) + 3);

        // ---- ECDF on window [kmin,kmax): contiguous chunk per thread, running pos
        //      (probe value cached in register to cut dependent LDS reads) ----
        {
            int W  = kmax - kmin;
            int k0 = kmin + ((tid * W) >> 8);
            int k1 = kmin + (((tid + 1) * W) >> 8);
            float fm = -100.0f;                  // force re-seed on first iter
            int pos = 0;
            int ci = -1;
            float cx0 = 0.f, cy0 = 0.f, cslope = 0.f;
            float snext = 0.f;                   // cached s_sorted[pos]
            for (int k = k0; k < k1; ++k) {
                float xn  = -1.0f + (float)k * step;
                float fm2 = floorf(xn);
                float r   = xn - fm2;
                if (fm2 != fm) {
                    fm = fm2;
                    int bq  = min((int)(r * 512.0f), NBIN - 1);
                    pos     = (int)s_prefix[bq];
                    int be  = (int)s_prefix[bq + 1];
                    while (pos < be && s_sorted[pos] < r) ++pos;
                    snext = (pos < NS) ? s_sorted[pos] : 2.0f;
                } else {
                    while (pos < NS && snext < r) {
                        ++pos;
                        snext = (pos < NS) ? s_sorted[pos] : 2.0f;
                    }
                }
                int i = min(max(pos - 1, 0), NS - 2);
                if (i != ci) {
                    ci = i;
                    cx0 = s_sorted[i];
                    cy0 = (float)(i + 1) * inv_n;
                    cslope = inv_n * fast_rcp(s_sorted[i + 1] - cx0);
                }
                s_ecdf[k] = fm + (cy0 + cslope * (r - cx0));
            }
        }
        // pre-zero histogram for input 2 (next use >= 2 barriers away)
        if (inp == 0) { s_hist[tid] = 0u; s_hist[tid + 256] = 0u; }
        __syncthreads();                                   // (G)

        // ---- bridge thresholds + seed routing (block-uniform). Array is monotone
        //      except possibly at (999,1000),(1999,2000). amb <=> q in a dip overlap.
        const float INF = 3.0e38f;
        bool in0 = (kmin <= 999)  && (1000 < kmax);
        bool in1 = (kmin <= 1999) && (2000 < kmax);
        float t0a = in0 ? s_ecdf[999]  : 0.f;
        float t0b = in0 ? s_ecdf[1000] : 0.f;   // t0b==t0a when !in0 -> amb false
        float t1a = in1 ? s_ecdf[1999] : 0.f;
        float t1b = in1 ? s_ecdf[2000] : 0.f;
        float rt0 = in0 ? t0b : ((kmin > 999)  ? -INF : INF);
        float rt1 = in1 ? t1b : ((kmin > 1999) ? -INF : INF);

        // ---- inverse: analytic seed + local scan (r8-verified); amb -> inline
        //      windowed array-bisect (r3/r9 semantics) ----
        if (j0 < NR) {
            int  k = kmin;
            bool have = false;
            #pragma unroll
            for (int jj = 0; jj < 4; ++jj) {
                float rj = (jj == 0) ? rj0 : (jj == 1) ? rj1 : (jj == 2) ? rj2 : rj3;
                float q = rj - alpha;
                float embv;
                bool amb = (q > t0b && q <= t0a) || (q > t1b && q <= t1a);
                if (amb) {
                    int lo = kmin, hi = kmax;
                    while (lo < hi) {
                        int mid = (lo + hi) >> 1;
                        if (s_ecdf[mid] < q) lo = mid + 1; else hi = mid;
                    }
                    int i = min(max(lo - 1, 0), NE - 2);
                    float e0 = s_ecdf[i];
                    float slope = step * fast_rcp(s_ecdf[i + 1] - e0);
                    float xn0 = -1.0f + (float)i * step;
                    float res = xn0 + slope * (q - e0);
                    embv = res - rj;
                } else {
                    if (!have) {
                        // analytic seed: invert chord structure of G (ys nodes uniform)
                        int m = (q > rt0) + (q > rt1) - 1;
                        float u = q - (float)m;
                        int istar = min(max((int)ceilf(u * 512.0f) - 2, 0), NS - 2);
                        float xa = s_sorted[istar];
                        float xb = s_sorted[istar + 1];
                        float rstar = fmaf(u - (float)(istar + 1) * inv_n,
                                           512.0f * (xb - xa), xa);
                        float xstar = (float)m + rstar;
                        k = min(max((int)ceilf((xstar + 1.0f) * invstep) - 1, kmin), kmax - 2);
                        have = true;
                    }
                    // unique crossing for non-amb q: local scan == bisect result
                    while (k < kmax - 2 && s_ecdf[k + 1] < q) ++k;
                    while (k > kmin && s_ecdf[k] >= q) --k;
                    float e0  = s_ecdf[k];
                    float e1c = s_ecdf[k + 1];
                    float slope = step * fast_rcp(e1c - e0);
                    float xn0 = -1.0f + (float)k * step;
                    float res = xn0 + slope * (q - e0);
                    embv = res - rj;
                }
                if (inp == 0) {
                    if (jj == 0) e1r0 = embv;
                    else if (jj == 1) e1r1 = embv;
                    else if (jj == 2) e1r2 = embv;
                    else e1r3 = embv;
                } else {
                    float ev = (jj == 0) ? e1r0 : (jj == 1) ? e1r1 : (jj == 2) ? e1r2 : e1r3;
                    float d = fabsf(embv - ev);
                    float c = fminf(d, 1.0f - d);
                    acc = fmaf(c, c, acc);
                }
            }
        }
        // NO end-of-input barrier needed (round-9 argument): inp0's inverse reads
        // only s_ecdf/s_sorted; inp1's first writes to those are its scatter/fill,
        // separated from here by inp1's barriers B..G. s_hist zeroing is ordered
        // by barrier G against inp1's atomics.
    }

    // ---- block reduce acc, sqrt, write per-row (s_devf dead, reuse) ----
    #pragma unroll
    for (int o = 32; o > 0; o >>= 1) acc += __shfl_down(acc, o, 64);
    if (lane == 0) s_devf[wave] = acc;
    __syncthreads();
    if (tid == 0) row_out[row] = sqrtf(s_devf[0] + s_devf[1] + s_devf[2] + s_devf[3]);
}

__global__ __launch_bounds__(256) void lcot_reduce_kernel(
    const float* __restrict__ row_vals, float* __restrict__ out)
{
    __shared__ float s_red[256];
    const int b = blockIdx.x;
    const int tid = threadIdx.x;
    float v = row_vals[b * NL + tid] + row_vals[b * NL + tid + 256];
    s_red[tid] = v;
    __syncthreads();
    for (int off = 128; off > 0; off >>= 1) {
        if (tid < off) s_red[tid] += s_red[tid + off];
        __syncthreads();
    }
    if (tid == 0) out[b] = s_red[0] * (1.0f / (float)NL);
}

extern "C" void kernel_launch(void* const* d_in, const int* in_sizes, int n_in,
                              void* d_out, int out_size, void* d_ws, size_t ws_size,
                              hipStream_t stream) {
    const float* x1  = (const float*)d_in[0];
    const float* x2  = (const float*)d_in[1];
    const float* ref = (const float*)d_in[2];
    float* out = (float*)d_out;
    float* row_vals = (float*)d_ws;   // NROWS floats of scratch

    lcot_row_kernel<<<NROWS, 256, 0, stream>>>(x1, x2, ref, row_vals);
    lcot_reduce_kernel<<<NB, 256, 0, stream>>>(row_vals, out);
}

// Round 12
// 103.119 us; speedup vs baseline: 1.1965x; 1.1511x over previous
//
#include <hip/hip_runtime.h>
#include <math.h>

// Problem constants (match reference)
#define NB 16       // batch
#define NL 512      // rows per batch
#define NS 512      // samples per row
#define NE 3000     // ecdf grid points (3*N_REF)
#define NR 1000     // ref points
#define NROWS (NB * NL)
#define NBIN 512    // counting-sort bins (avg 1 sample/bin)

__device__ __forceinline__ float fast_rcp(float x) { return __builtin_amdgcn_rcpf(x); }

__global__ __launch_bounds__(256) void lcot_row_kernel(
    const float* __restrict__ x1, const float* __restrict__ x2,
    const float* __restrict__ ref, float* __restrict__ row_out)
{
    __shared__ float    s_sorted[NS];
    __shared__ unsigned s_hist[NBIN];       // histogram, then scatter cursor
    __shared__ unsigned s_prefix[NBIN + 1]; // exclusive prefix (stable)
    __shared__ float    s_ecdf[NE];         // filled only on [kmin,kmax)
    __shared__ float    s_alpA[4], s_alpB[4]; // alpha partials per input
    __shared__ float    s_devf[4];          // dev partials / final acc partials
    __shared__ unsigned s_wredu[4];

    const int tid  = threadIdx.x;
    const int lane = tid & 63;
    const int wave = tid >> 6;
    const int row  = blockIdx.x;
    const float inv_n   = 1.0f / 512.0f;            // exact
    const float step    = (float)(3.0 / 2999.0);    // linspace(-1,2,3000) spacing
    const float invstep = 2999.0f / 3.0f;

    // preload this thread's 4 query refs once (threads 250..255 idle in inverse)
    const int j0 = tid * 4;
    float rj0 = 0.f, rj1 = 0.f, rj2 = 0.f, rj3 = 0.f;
    if (j0 < NR) {
        float4 r4 = ((const float4*)ref)[tid];
        rj0 = r4.x; rj1 = r4.y; rj2 = r4.z; rj3 = r4.w;
    }
    float e1r0 = 0.f, e1r1 = 0.f, e1r2 = 0.f, e1r3 = 0.f;   // e1 kept in registers

    // prefetch BOTH rows up front (overlap HBM latency once)
    const float* srcA = x1 + (size_t)row * NS;
    const float* srcB = x2 + (size_t)row * NS;
    float a0 = srcA[tid], a1 = srcA[tid + 256];
    float c0 = srcB[tid], c1 = srcB[tid + 256];

    float acc = 0.0f;

    for (int inp = 0; inp < 2; ++inp) {
        float v0 = (inp == 0) ? a0 : c0;
        float v1 = (inp == 0) ? a1 : c1;

        if (inp == 0) {
            // zero histogram + BOTH inputs' alpha partial sums (once)
            s_hist[tid] = 0u;
            s_hist[tid + 256] = 0u;
            float sA = a0 + a1, sB = c0 + c1;
            #pragma unroll
            for (int o = 32; o > 0; o >>= 1) {
                sA += __shfl_down(sA, o, 64);
                sB += __shfl_down(sB, o, 64);
            }
            if (lane == 0) { s_alpA[wave] = sA; s_alpB[wave] = sB; }
            __syncthreads();                               // (A)
        }
        // (for inp==1: hist pre-zeroed during inp0's fill region, >=2 barriers ago)

        // ---- histogram ----
        int b0 = min((int)(v0 * 512.0f), NBIN - 1);
        int b1 = min((int)(v1 * 512.0f), NBIN - 1);
        atomicAdd(&s_hist[b0], 1u);
        atomicAdd(&s_hist[b1], 1u);
        __syncthreads();                                   // (B)

        const float* alp = (inp == 0) ? s_alpA : s_alpB;
        float alpha = (alp[0] + alp[1] + alp[2] + alp[3]) * inv_n - 0.5f;

        // ---- exclusive prefix over 512 bins (2 consecutive bins / thread) ----
        unsigned h0 = s_hist[2 * tid];
        unsigned h1 = s_hist[2 * tid + 1];
        unsigned ls = h0 + h1;
        unsigned sc0 = ls;                                 // wave inclusive scan
        #pragma unroll
        for (int o = 1; o < 64; o <<= 1) {
            unsigned t2 = __shfl_up(sc0, o, 64);
            if (lane >= o) sc0 += t2;
        }
        if (lane == 63) s_wredu[wave] = sc0;
        __syncthreads();                                   // (C)
        unsigned wbase0 = 0;
        for (int w = 0; w < 4; ++w) if (w < wave) wbase0 += s_wredu[w];
        unsigned base = wbase0 + sc0 - ls;                 // exclusive base for bin 2*tid
        s_prefix[2 * tid]     = base;
        s_prefix[2 * tid + 1] = base + h0;
        s_hist[2 * tid]       = base;                      // scatter cursors
        s_hist[2 * tid + 1]   = base + h0;
        if (tid == 255) s_prefix[NBIN] = (unsigned)NS;
        __syncthreads();                                   // (D)

        // ---- scatter + PROVISIONAL node-deviation (slot vs true rank differ by
        //      <= bin_count-1; covered by +12/512 slop on D below) ----
        unsigned p0 = atomicAdd(&s_hist[b0], 1u);
        s_sorted[p0] = v0;
        unsigned p1 = atomicAdd(&s_hist[b1], 1u);
        s_sorted[p1] = v1;
        float dv = fmaxf(fabsf((float)(p0 + 1) * inv_n - v0),
                         fabsf((float)(p1 + 1) * inv_n - v1));
        #pragma unroll
        for (int o = 32; o > 0; o >>= 1) dv = fmaxf(dv, __shfl_down(dv, o, 64));
        if (lane == 0) s_devf[wave] = dv;
        __syncthreads();                                   // (E)

        // ---- per-bin insertion sort (exact; bins avg 1 element) ----
        for (int bb = tid; bb < NBIN; bb += 256) {
            int beg = (int)s_prefix[bb];
            int end = (int)s_prefix[bb + 1];
            for (int i2 = beg + 1; i2 < end; ++i2) {
                float key = s_sorted[i2];
                int jj = i2 - 1;
                while (jj >= beg && s_sorted[jj] > key) { s_sorted[jj + 1] = s_sorted[jj]; --jj; }
                s_sorted[jj + 1] = key;
            }
        }
        __syncthreads();                                   // (F)

        // ---- deviation bound D (node partials + exact extrapolation endpoints) ----
        float Dm = fmaxf(fmaxf(s_devf[0], s_devf[1]), fmaxf(s_devf[2], s_devf[3]));
        {
            float sa0 = s_sorted[0], sa1 = s_sorted[1];
            float sbA = s_sorted[510], sbB = s_sorted[511];
            float sl0 = inv_n * fast_rcp(sa1 - sa0);
            float slR = inv_n * fast_rcp(sbB - sbA);
            float lext = fabsf(inv_n - sl0 * sa0);
            float rext = fabsf(511.0f * inv_n + slR * (1.0f - sbA) - 1.0f);
            Dm = fmaxf(Dm, fmaxf(lext, rext));
        }
        float D = Dm + 0.0249f;   // provisional-rank slop + fp margin

        float qlo = 0.0f - alpha;
        float qhi = 0.999f - alpha;
        int kmin = max(0,  (int)((qlo + 1.0f - D) * invstep) - 2);
        int kmax = min(NE, (int)((qhi + 1.0f + D) * invstep) + 3);

        // ---- ECDF on window [kmin,kmax): contiguous chunk per thread, split at
        //      the (at most one) segment boundary so the per-cell loop has constant
        //      fm (no floorf / fm-compare). Seed logic identical to fm-change path. ----
        {
            int W  = kmax - kmin;
            int k0 = kmin + ((tid * W) >> 8);
            int k1 = kmin + (((tid + 1) * W) >> 8);
            if (k0 < k1) {
                int sgA = k0 / 1000;
                int sgB = (k1 - 1) / 1000;
                for (int sg = sgA; sg <= sgB; ++sg) {
                    int ka = max(k0, sg * 1000);
                    int kb = min(k1, sg * 1000 + 1000);
                    float fm = (float)(sg - 1);
                    // seed pos = #samples < r(ka) via bin table (exact)
                    float xn0 = -1.0f + (float)ka * step;
                    float r0  = xn0 - fm;
                    int bq  = min((int)(r0 * 512.0f), NBIN - 1);
                    int pos = (int)s_prefix[bq];
                    int be  = (int)s_prefix[bq + 1];
                    while (pos < be && s_sorted[pos] < r0) ++pos;
                    float snext = (pos < NS) ? s_sorted[pos] : 2.0f;
                    int i = min(max(pos - 1, 0), NS - 2);
                    int ci = i;
                    float cx0 = s_sorted[i];
                    float cy0 = (float)(i + 1) * inv_n;
                    float csl = inv_n * fast_rcp(s_sorted[i + 1] - cx0);
                    for (int k = ka; k < kb; ++k) {
                        float xn = -1.0f + (float)k * step;
                        float r  = xn - fm;
                        while (pos < NS && snext < r) {
                            ++pos;
                            snext = (pos < NS) ? s_sorted[pos] : 2.0f;
                        }
                        i = min(max(pos - 1, 0), NS - 2);
                        if (i != ci) {
                            ci = i;
                            cx0 = s_sorted[i];
                            cy0 = (float)(i + 1) * inv_n;
                            csl = inv_n * fast_rcp(s_sorted[i + 1] - cx0);
                        }
                        s_ecdf[k] = fm + (cy0 + csl * (r - cx0));
                    }
                }
            }
        }
        // pre-zero histogram for input 2 (next use >= 2 barriers away)
        if (inp == 0) { s_hist[tid] = 0u; s_hist[tid + 256] = 0u; }
        __syncthreads();                                   // (G)

        // ---- inverse CDF at 4 contiguous queries/thread: D-narrowed bisect for
        //      the first query (every crossing of q provably lies in
        //      [(q-D+1)*invstep-2, (q+D+1)*invstep+3) -- same margins as window),
        //      then forward scan for the ascending rest ----
        if (j0 < NR) {
            float q = rj0 - alpha;
            int lo = max(kmin, (int)((q - D + 1.0f) * invstep) - 2);
            int hi = min(kmax, (int)((q + D + 1.0f) * invstep) + 3);
            while (lo < hi) {                               // bisect_left (narrowed)
                int mid = (lo + hi) >> 1;
                if (s_ecdf[mid] < q) lo = mid + 1; else hi = mid;
            }
            int pos2 = lo;
            #pragma unroll
            for (int jj = 0; jj < 4; ++jj) {
                float rj = (jj == 0) ? rj0 : (jj == 1) ? rj1 : (jj == 2) ? rj2 : rj3;
                q = rj - alpha;
                if (jj > 0) while (pos2 < NE && s_ecdf[pos2] < q) ++pos2;
                int i = min(max(pos2 - 1, 0), NE - 2);
                float e0 = s_ecdf[i];
                float slope = step * fast_rcp(s_ecdf[i + 1] - e0);
                float xn0 = -1.0f + (float)i * step;
                float res = xn0 + slope * (q - e0);
                float embv = res - rj;
                if (inp == 0) {
                    if (jj == 0) e1r0 = embv;
                    else if (jj == 1) e1r1 = embv;
                    else if (jj == 2) e1r2 = embv;
                    else e1r3 = embv;
                } else {
                    float ev = (jj == 0) ? e1r0 : (jj == 1) ? e1r1 : (jj == 2) ? e1r2 : e1r3;
                    float d = fabsf(embv - ev);
                    float c = fminf(d, 1.0f - d);
                    acc = fmaf(c, c, acc);
                }
            }
        }
        // NO end-of-input barrier needed (round-9 argument): inp0's inverse reads
        // only s_ecdf/s_sorted; inp1's first writes to those are its scatter/fill,
        // separated from here by inp1's barriers B..G. s_hist zeroing is ordered
        // by barrier G against inp1's atomics.
    }

    // ---- block reduce acc, sqrt, write per-row (s_devf dead, reuse) ----
    #pragma unroll
    for (int o = 32; o > 0; o >>= 1) acc += __shfl_down(acc, o, 64);
    if (lane == 0) s_devf[wave] = acc;
    __syncthreads();
    if (tid == 0) row_out[row] = sqrtf(s_devf[0] + s_devf[1] + s_devf[2] + s_devf[3]);
}

__global__ __launch_bounds__(256) void lcot_reduce_kernel(
    const float* __restrict__ row_vals, float* __restrict__ out)
{
    __shared__ float s_red[256];
    const int b = blockIdx.x;
    const int tid = threadIdx.x;
    float v = row_vals[b * NL + tid] + row_vals[b * NL + tid + 256];
    s_red[tid] = v;
    __syncthreads();
    for (int off = 128; off > 0; off >>= 1) {
        if (tid < off) s_red[tid] += s_red[tid + off];
        __syncthreads();
    }
    if (tid == 0) out[b] = s_red[0] * (1.0f / (float)NL);
}

extern "C" void kernel_launch(void* const* d_in, const int* in_sizes, int n_in,
                              void* d_out, int out_size, void* d_ws, size_t ws_size,
                              hipStream_t stream) {
    const float* x1  = (const float*)d_in[0];
    const float* x2  = (const float*)d_in[1];
    const float* ref = (const float*)d_in[2];
    float* out = (float*)d_out;
    float* row_vals = (float*)d_ws;   // NROWS floats of scratch

    lcot_row_kernel<<<NROWS, 256, 0, stream>>>(x1, x2, ref, row_vals);
    lcot_reduce_kernel<<<NB, 256, 0, stream>>>(row_vals, out);
}